// Round 1
// baseline (139.252 us; speedup 1.0000x reference)
//
#include <hip/hip_runtime.h>
#include <hip/hip_bf16.h>

#define NEG_INF (-__builtin_inff())

// Each thread: all Co=8 outputs for 4 consecutive w pixels at one (n,h).
// Block = 256 threads = 2 output rows x 128 w-groups (coalesced float4).
// Grid = N * H/2 = 2048 blocks.
__global__ __launch_bounds__(256) void dil2d_kernel(const float* __restrict__ x,
                                                    const float* __restrict__ w,
                                                    float* __restrict__ out) {
    const int Ci = 4, Co = 8, H = 512, W = 512;

    const int tid = threadIdx.x;
    const int wg  = tid & 127;      // w-group 0..127
    const int w0  = wg << 2;        // 0..508
    const int rib = tid >> 7;       // row in block 0..1
    const int b   = blockIdx.x;
    const int n   = b >> 8;         // / 256
    const int h   = ((b & 255) << 1) + rib;

    float acc[Co][4];
#pragma unroll
    for (int co = 0; co < Co; ++co)
#pragma unroll
        for (int j = 0; j < 4; ++j) acc[co][j] = NEG_INF;

    const float* xn = x + n * (Ci * H * W);

    for (int ci = 0; ci < Ci; ++ci) {
        const float* xc = xn + ci * (H * W);
        const float* wc = w + ci * 25;
        for (int kh = 0; kh < 5; ++kh) {
            const int r = h + kh - 2;
            if (r < 0 || r >= H) continue;   // wave-uniform branch
            const float* xr = xc + r * W;

            // window xv[0..7] = x[r][w0-2 .. w0+5], -inf outside image
            float xv[8];
            {
                const int off_lo = (w0 == 0)   ? 0   : (w0 - 2);  // 8B aligned
                const int off_hi = (w0 == 508) ? 508 : (w0 + 4);  // 8B aligned
                const float2 lo  = *(const float2*)(xr + off_lo);
                const float4 mid = *(const float4*)(xr + w0);
                const float2 hi  = *(const float2*)(xr + off_hi);
                xv[0] = (w0 == 0)   ? NEG_INF : lo.x;
                xv[1] = (w0 == 0)   ? NEG_INF : lo.y;
                xv[2] = mid.x; xv[3] = mid.y; xv[4] = mid.z; xv[5] = mid.w;
                xv[6] = (w0 == 508) ? NEG_INF : hi.x;
                xv[7] = (w0 == 508) ? NEG_INF : hi.y;
            }

            const float* wk = wc + kh * 5;   // uniform -> scalar loads
#pragma unroll
            for (int co = 0; co < Co; ++co) {
                const float* wco = wk + co * (Ci * 25);
                const float wv0 = wco[0], wv1 = wco[1], wv2 = wco[2],
                            wv3 = wco[3], wv4 = wco[4];
#pragma unroll
                for (int j = 0; j < 4; ++j) {
                    float m  = acc[co][j];
                    float t0 = xv[j]     + wv0;
                    float t1 = xv[j + 1] + wv1;
                    m = fmaxf(m, fmaxf(t0, t1));          // -> v_max3_f32
                    float t2 = xv[j + 2] + wv2;
                    float t3 = xv[j + 3] + wv3;
                    m = fmaxf(m, fmaxf(t2, t3));          // -> v_max3_f32
                    m = fmaxf(m, xv[j + 4] + wv4);
                    acc[co][j] = m;
                }
            }
        }
    }

    float* on = out + n * (Co * H * W) + h * W + w0;
#pragma unroll
    for (int co = 0; co < Co; ++co) {
        float4 v = make_float4(acc[co][0], acc[co][1], acc[co][2], acc[co][3]);
        *(float4*)(on + co * (H * W)) = v;
    }
}

extern "C" void kernel_launch(void* const* d_in, const int* in_sizes, int n_in,
                              void* d_out, int out_size, void* d_ws, size_t ws_size,
                              hipStream_t stream) {
    const float* x = (const float*)d_in[0];
    const float* w = (const float*)d_in[1];
    float* out     = (float*)d_out;

    dim3 grid(2048), block(256);
    hipLaunchKernelGGL(dil2d_kernel, grid, block, 0, stream, x, w, out);
}